// Round 1
// baseline (152.829 us; speedup 1.0000x reference)
//
#include <hip/hip_runtime.h>
#include <math.h>

// Problem: pair-embedding scorer. 4 stacked Linear layers with NO intermediate
// activation => the whole MLP is one affine map. We fold W1@W2@W3@W4 into a
// single 1802-vector v1 and scalar bias c, precompute per-entity partial dots
// sA/sB against feature rows, then the per-sample work is two table lookups,
// an add, and a sigmoid.
//
// ws layout (floats):
//   [0      .. 512)    v3
//   [512    .. 1536)   v2
//   [1536   .. 3338)   v1
//   [3338]             c (scalar)
//   [4096   .. 24096)  sA (20000)
//   [24096  .. 44096)  sB (20000)

#define WAVE 64

__device__ inline float wave_reduce_sum(float v) {
    #pragma unroll
    for (int off = 32; off; off >>= 1) v += __shfl_down(v, off, 64);
    return v;
}

// c = b4[0]
__global__ void init_c(float* __restrict__ c, const float* __restrict__ b4) {
    *c = *b4;
}

// Wave-per-row matvec: y[i] = dot(W[i, 0:K], x) for i in [0, M).
// Extra wave (id == M) accumulates c += dot(bias, x).
// Coalesced: lane-strided reads of each row.
__global__ void matvec_rows(const float* __restrict__ W,
                            const float* __restrict__ x,
                            float* __restrict__ y,
                            const float* __restrict__ bias,
                            float* __restrict__ c,
                            int M, int K) {
    int gwave = (blockIdx.x * blockDim.x + threadIdx.x) >> 6;
    int lane  = threadIdx.x & 63;
    if (gwave > M) return;
    if (gwave == M) {
        float acc = 0.f;
        for (int k = lane; k < K; k += WAVE) acc += bias[k] * x[k];
        acc = wave_reduce_sum(acc);
        if (lane == 0) atomicAdd(c, acc);   // single wave writes; stages are stream-ordered
        return;
    }
    const float* row = W + (size_t)gwave * (size_t)K;
    float acc = 0.f;
    for (int k = lane; k < K; k += WAVE) acc += row[k] * x[k];
    acc = wave_reduce_sum(acc);
    if (lane == 0) y[gwave] = acc;
}

// Wave-per-entity: one pass over feature[e, 0:901] computing both half-dots.
// D=901 floats/row; lane-strided scalar loads are coalesced (64B segments).
__global__ void feat_fold(const float* __restrict__ F,
                          const float* __restrict__ v1,
                          float* __restrict__ sA,
                          float* __restrict__ sB,
                          int NE, int D) {
    int gwave = (blockIdx.x * blockDim.x + threadIdx.x) >> 6;
    int lane  = threadIdx.x & 63;
    if (gwave >= NE) return;
    const float* row = F + (size_t)gwave * (size_t)D;
    const float* va  = v1;
    const float* vb  = v1 + D;
    float a = 0.f, b = 0.f;
    for (int d = lane; d < D; d += WAVE) {
        float f = row[d];           // HBM-bound stream
        a += f * va[d];             // va/vb: wave-uniform-ish, L1/L2 broadcast
        b += f * vb[d];
    }
    a = wave_reduce_sum(a);
    b = wave_reduce_sum(b);
    if (lane == 0) { sA[gwave] = a; sB[gwave] = b; }
}

// out[i] = sigmoid(sA[p0] + sB[p1] + c) for train then test, concatenated.
__global__ void head(const int* __restrict__ tr, const int* __restrict__ te,
                     const float* __restrict__ sA, const float* __restrict__ sB,
                     const float* __restrict__ c, float* __restrict__ out,
                     int ntr, int nte) {
    int i = blockIdx.x * blockDim.x + threadIdx.x;
    int n = ntr + nte;
    if (i >= n) return;
    int p0, p1;
    if (i < ntr) { p0 = tr[2 * i];          p1 = tr[2 * i + 1]; }
    else         { int j = i - ntr; p0 = te[2 * j]; p1 = te[2 * j + 1]; }
    float x = sA[p0] + sB[p1] + *c;         // sA/sB = 160 KB total -> L2-resident
    out[i] = 1.0f / (1.0f + __expf(-x));
}

extern "C" void kernel_launch(void* const* d_in, const int* in_sizes, int n_in,
                              void* d_out, int out_size, void* d_ws, size_t ws_size,
                              hipStream_t stream) {
    const float* feature = (const float*)d_in[0];   // [20000, 901]
    const float* W1      = (const float*)d_in[1];   // [1802, 1024]
    const float* b1      = (const float*)d_in[2];   // [1024]
    const float* W2      = (const float*)d_in[3];   // [1024, 512]
    const float* b2      = (const float*)d_in[4];   // [512]
    const float* W3      = (const float*)d_in[5];   // [512, 64]
    const float* b3      = (const float*)d_in[6];   // [64]
    const float* W4      = (const float*)d_in[7];   // [64, 1] -> v4 (64 floats)
    const float* b4      = (const float*)d_in[8];   // [1]
    const int*   tr      = (const int*)d_in[9];     // [100000, 2]
    const int*   te      = (const int*)d_in[10];    // [25000, 2]
    float*       out     = (float*)d_out;           // [125000]

    const int NE = 20000, D = 901;
    const int NTR = in_sizes[9] / 2;    // 100000
    const int NTE = in_sizes[10] / 2;   // 25000

    float* ws = (float*)d_ws;
    float* v3 = ws;
    float* v2 = ws + 512;
    float* v1 = ws + 1536;
    float* c  = ws + 3338;
    float* sA = ws + 4096;
    float* sB = ws + 24096;

    // c = b4 (ws is re-poisoned each call; must init)
    init_c<<<1, 1, 0, stream>>>(c, b4);

    // v3 = W3 @ v4 ; c += b3 . v4
    {
        int waves = 512 + 1;
        int blocks = (waves * 64 + 255) / 256;
        matvec_rows<<<blocks, 256, 0, stream>>>(W3, W4, v3, b3, c, 512, 64);
    }
    // v2 = W2 @ v3 ; c += b2 . v3
    {
        int waves = 1024 + 1;
        int blocks = (waves * 64 + 255) / 256;
        matvec_rows<<<blocks, 256, 0, stream>>>(W2, v3, v2, b2, c, 1024, 512);
    }
    // v1 = W1 @ v2 ; c += b1 . v2
    {
        int waves = 1802 + 1;
        int blocks = (waves * 64 + 255) / 256;
        matvec_rows<<<blocks, 256, 0, stream>>>(W1, v2, v1, b1, c, 1802, 1024);
    }
    // sA/sB = feature . v1 halves  (the only big kernel: 72 MB stream)
    {
        int waves = NE;                        // 20000 waves, 4/block
        int blocks = (waves * 64 + 255) / 256; // 5000 blocks
        feat_fold<<<blocks, 256, 0, stream>>>(feature, v1, sA, sB, NE, D);
    }
    // out = sigmoid(sA[p0] + sB[p1] + c)
    {
        int n = NTR + NTE;
        int blocks = (n + 255) / 256;
        head<<<blocks, 256, 0, stream>>>(tr, te, sA, sB, c, out, NTR, NTE);
    }
}